// Round 8
// baseline (282.460 us; speedup 1.0000x reference)
//
#include <hip/hip_runtime.h>
#include <hip/hip_bf16.h>

// SimpleAugmentedCNN forward, B=16, H=W=32, NH=4, DKH=DVH=10.
// 5 dispatches: memset(acc) -> conv1(LDS-staged, +BN-stat atomics) ->
// qkv3(BN+relu+sstat+1x1) -> attn_mfma -> final.
// attn_mfma: 32x32x16 bf16; S^T=K.Q^T (C col=query, row=key); rw folded as
// C-init; rh via spare dim10 from packed regs; softmax denom via ones-row in
// V; P feeds PV MFMA *lane-locally* via V key-slot bit2<->3 swap (no LDS
// round-trip, no shuffles); avg-pool fused with atomics.
// conv_out / attention map / attn_pre never materialized.

#define WS_H     0                      // 16*64*1024   = 1048576 floats
#define WS_QKV   1048576                // 16*120*1024  = 1966080
#define WS_ACC   3014656                // chanS 64 | chanS2 64 | sstatP 5120 | pooledA 640
#define ACC_BYTES ((64 + 64 + 5120 + 640) * 4)

typedef __attribute__((ext_vector_type(8))) short short8;
typedef __attribute__((ext_vector_type(16))) float float16;

__device__ __forceinline__ float fast_exp2(float x) {
#if __has_builtin(__builtin_amdgcn_exp2f)
  return __builtin_amdgcn_exp2f(x);
#else
  return exp2f(x);
#endif
}
__device__ __forceinline__ short f2bf(float x) {
  __hip_bfloat16 h(x);                 // RNE
  return *reinterpret_cast<short*>(&h);
}
__device__ __forceinline__ float bf2f(short s) {
  return __uint_as_float(((unsigned)(unsigned short)s) << 16);
}
__device__ __forceinline__ unsigned pack_bf16(float a, float b) {
  return (__float_as_uint(a) >> 16) | (__float_as_uint(b) & 0xFFFF0000u);
}

// ---------------- conv1: 3->64 3x3 SAME, LDS-staged x, 2 co/block -----------
__global__ __launch_bounds__(256) void conv1_kernel(
    const float* __restrict__ x, const float* __restrict__ w,
    const float* __restrict__ bias, float* __restrict__ h,
    float* __restrict__ chanS, float* __restrict__ chanS2) {
  int b = blockIdx.x >> 5, cg = blockIdx.x & 31;
  int co0 = cg * 2;
  int t = threadIdx.x;
  __shared__ float xs[3072];
  const float4* xg = reinterpret_cast<const float4*>(x + b * 3072);
  float4* xsv = reinterpret_cast<float4*>(xs);
  for (int i = t; i < 768; i += 256) xsv[i] = xg[i];

  typedef const __attribute__((address_space(4))) float* cfp;
  cfp wc = (cfp)(size_t)w;
  float wr0[27], wr1[27];
#pragma unroll
  for (int i = 0; i < 27; ++i) { wr0[i] = wc[co0 * 27 + i]; wr1[i] = wc[(co0 + 1) * 27 + i]; }
  float bv0 = bias[co0], bv1 = bias[co0 + 1];
  __syncthreads();

  int row = t >> 3, col0 = (t & 7) * 4;
  float acc0[4] = {bv0, bv0, bv0, bv0};
  float acc1[4] = {bv1, bv1, bv1, bv1};
#pragma unroll
  for (int ci = 0; ci < 3; ++ci) {
#pragma unroll
    for (int dy = 0; dy < 3; ++dy) {
      int sr = row + dy - 1;
      if (sr < 0 || sr > 31) continue;
      const float* xr = &xs[ci * 1024 + sr * 32];
      float xv[6];
#pragma unroll
      for (int j = 0; j < 6; ++j) {
        int c = col0 - 1 + j;
        xv[j] = (c >= 0 && c < 32) ? xr[c] : 0.f;
      }
#pragma unroll
      for (int dx = 0; dx < 3; ++dx) {
        float w0 = wr0[ci * 9 + dy * 3 + dx], w1 = wr1[ci * 9 + dy * 3 + dx];
#pragma unroll
        for (int k = 0; k < 4; ++k) {
          acc0[k] += w0 * xv[k + dx];
          acc1[k] += w1 * xv[k + dx];
        }
      }
    }
  }
  *reinterpret_cast<float4*>(&h[(size_t)(b * 64 + co0) * 1024 + t * 4]) =
      make_float4(acc0[0], acc0[1], acc0[2], acc0[3]);
  *reinterpret_cast<float4*>(&h[(size_t)(b * 64 + co0 + 1) * 1024 + t * 4]) =
      make_float4(acc1[0], acc1[1], acc1[2], acc1[3]);

  float s10 = acc0[0] + acc0[1] + acc0[2] + acc0[3];
  float s20 = acc0[0]*acc0[0] + acc0[1]*acc0[1] + acc0[2]*acc0[2] + acc0[3]*acc0[3];
  float s11 = acc1[0] + acc1[1] + acc1[2] + acc1[3];
  float s21 = acc1[0]*acc1[0] + acc1[1]*acc1[1] + acc1[2]*acc1[2] + acc1[3]*acc1[3];
#pragma unroll
  for (int off = 32; off > 0; off >>= 1) {
    s10 += __shfl_down(s10, off);
    s20 += __shfl_down(s20, off);
    s11 += __shfl_down(s11, off);
    s21 += __shfl_down(s21, off);
  }
  if ((t & 63) == 0) {
    atomicAdd(&chanS[co0], s10);
    atomicAdd(&chanS2[co0], s20);
    atomicAdd(&chanS[co0 + 1], s11);
    atomicAdd(&chanS2[co0 + 1], s21);
  }
}

// ---------------- qkv3: BN-apply + relu + sstat partials + qkv 1x1 ----------
__global__ __launch_bounds__(256) void qkv_kernel3(
    const float* __restrict__ h, const float* __restrict__ chanS,
    const float* __restrict__ chanS2, const float* __restrict__ bn_g,
    const float* __restrict__ bn_b, const float* __restrict__ qw,
    const float* __restrict__ qb, float* __restrict__ qkv,
    float* __restrict__ sstatP) {
  int bid = blockIdx.x;
  int half = bid & 1, ck = (bid >> 1) & 15, b = bid >> 5;
  int t = threadIdx.x;
  __shared__ float ssc[64], ssh[64];
  __shared__ float hs[64][65];
  if (t < 64) {
    float mu = chanS[t] * (1.f / 16384.f);
    float var = chanS2[t] * (1.f / 16384.f) - mu * mu;
    float sc = bn_g[t] * rsqrtf(var + 1e-5f);
    ssc[t] = sc;
    ssh[t] = bn_b[t] - mu * sc;
  }
  __syncthreads();
  int pos = t & 63, grp = t >> 6;
#pragma unroll
  for (int r = 0; r < 16; ++r) {
    int ci = r * 4 + grp;
    float v = h[(size_t)(b * 64 + ci) * 1024 + ck * 64 + pos];
    hs[ci][pos] = fmaxf(0.f, v * ssc[ci] + ssh[ci]);
  }
  __syncthreads();
  if (half == 0 && t < 128) {
    int ci = t >> 1, rl = t & 1;
    int row = ck * 2 + rl;
    const float* hp = &hs[ci][rl * 32];
    float T = 0.f;
#pragma unroll
    for (int k = 0; k < 32; ++k) T += hp[k];
    float* sp = sstatP + (size_t)(b * 64 + ci) * 5;
    atomicAdd(sp + 0, T);
    if (row == 0) atomicAdd(sp + 1, T);
    if (row == 31) atomicAdd(sp + 2, T);
    atomicAdd(sp + 3, hp[0]);
    atomicAdd(sp + 4, hp[31]);
  }
  int co0 = half * 60 + grp * 15;
  float acc[15];
#pragma unroll
  for (int j = 0; j < 15; ++j) acc[j] = 0.f;
  typedef const __attribute__((address_space(4))) float* cfp;
  cfp qwc = (cfp)(size_t)qw;
  for (int ci = 0; ci < 64; ++ci) {
    float hv = hs[ci][pos];
#pragma unroll
    for (int j = 0; j < 15; ++j) acc[j] += qwc[(co0 + j) * 64 + ci] * hv;
  }
#pragma unroll
  for (int j = 0; j < 15; ++j)
    qkv[(size_t)(b * 120 + co0 + j) * 1024 + ck * 64 + pos] = acc[j] + qb[co0 + j];
}

// ---------------- MFMA attention, lane-local P, fused pool ------------------
// grid 512 = b*32 + hd*8 + qt; block 256 = 4 waves; wave = 32 queries x 1024 keys.
// V staged with key-slot bits 2<->3 swapped so the QK^T C-regs ARE the PV
// B-frags (e[0..7] -> MFMA#1, e[8..15] -> MFMA#2), no cross-lane movement.
__global__ __launch_bounds__(256, 4) void attn_mfma_kernel(
    const float* __restrict__ qkv, const float* __restrict__ relw,
    const float* __restrict__ relh, float* __restrict__ pooledA) {
  int bid = blockIdx.x;
  int qt = bid & 7, hd = (bid >> 3) & 3, b = bid >> 5;
  int t = threadIdx.x;
  int lane = t & 63, w = t >> 6, lid = lane & 31, hi = lane >> 5;

  __shared__ __align__(16) short Ks[256 * 24];   // [key][24] bf16 (d10=1, 11..15=0)
  __shared__ __align__(16) short Vs[16 * 264];   // [dim][264] bf16 (row10=1)
  __shared__ float poolL[16];

  short* Qs = Ks;                     // overlay [128][16] (setup only)
  float* RwL = (float*)Vs;            // [63][10] fp32 (setup only)
  float* RhL = RwL + 630;

  if (t < 16) poolL[t] = 0.f;
  const float QS2 = 0.31622776601683794f * 1.4426950408889634f;  // dkh^-0.5 * log2e
  const float* qg = qkv + (size_t)(b * 120 + hd * 10) * 1024 + qt * 128;
  for (int i = t; i < 630; i += 256) {
    RwL[i] = relw[i];
    RhL[i] = relh[i];
  }
  for (int i = t; i < 1280; i += 256) {
    int q = i & 127, d = i >> 7;
    Qs[q * 16 + d] = f2bf(qg[d * 1024 + q] * QS2);
  }
  __syncthreads();

  int qrow = w * 32 + lid;            // block-local query
  float qfv[10];
#pragma unroll
  for (int d = 0; d < 10; ++d) qfv[d] = bf2f(Qs[qrow * 16 + d]);

  // rw C-init: rwC[r] = dot(q, Rw[31 + y'(r) - y(q)]), y(q)=lid, y'(r)=C-row
  float16 rwC;
#pragma unroll
  for (int r = 0; r < 16; ++r) {
    int yp = (r & 3) + 8 * (r >> 2) + 4 * hi;
    const float* rp = &RwL[(31 + yp - lid) * 10];
    float s = 0.f;
#pragma unroll
    for (int d = 0; d < 10; ++d) s += qfv[d] * rp[d];
    rwC[r] = s;
  }
  // rh for all 32 tiles (x' = 0..31), packed bf16 pairs in 16 regs
  int xn = qt * 4 + w;
  unsigned rhp[16];
#pragma unroll
  for (int j = 0; j < 16; ++j) {
    const float* rpa = &RhL[(31 + 2 * j - xn) * 10];
    const float* rpb = &RhL[(31 + 2 * j + 1 - xn) * 10];
    float sa = 0.f, sb = 0.f;
#pragma unroll
    for (int d = 0; d < 10; ++d) { sa += qfv[d] * rpa[d]; sb += qfv[d] * rpb[d]; }
    rhp[j] = pack_bf16(sa, sb);
  }
  // Q B-frag (col=q, k=dims)
  short8 qf = *reinterpret_cast<const short8*>(&Qs[qrow * 16 + hi * 8]);
  short qf2 = qf[2];
  if (hi) { qf[3] = 0; qf[4] = 0; qf[5] = 0; qf[6] = 0; qf[7] = 0; }

  float16 O;
#pragma unroll
  for (int i = 0; i < 16; ++i) O[i] = 0.f;

  const float* kg = qkv + (size_t)(b * 120 + 40 + hd * 10) * 1024;
  const float* vg = kg + 40 * 1024;

  for (int p = 0; p < 4; ++p) {
    __syncthreads();   // overlays consumed (p=0) / prev pass reads done
    for (int i = t; i < 2560; i += 256) {
      int d = i >> 8, key = i & 255;
      Ks[key * 24 + d] = f2bf(kg[d * 1024 + p * 256 + key]);
      // V column: swap bits 2<->3 of within-32 key index
      int kc = (key & ~0x0C & 0xFF) ;
      kc = (key & 0xF3) | ((key & 4) << 1) | ((key & 8) >> 1);
      Vs[d * 264 + kc] = f2bf(vg[d * 1024 + p * 256 + key]);
    }
    Ks[t * 24 + 10] = (short)0x3F80;   // K dim10 = 1.0 (rh carrier)
#pragma unroll
    for (int d2 = 11; d2 < 16; ++d2) Ks[t * 24 + d2] = 0;  // NaN guard
    Vs[10 * 264 + t] = (short)0x3F80;  // ones-row (denominator)
    __syncthreads();

#pragma unroll
    for (int tt = 0; tt < 8; ++tt) {
      int Tl = p * 8 + tt;
      unsigned rhw = rhp[Tl >> 1];
      short rhu = (short)((Tl & 1) ? (rhw >> 16) : (rhw & 0xFFFFu));
      short8 bq = qf;
      bq[2] = hi ? rhu : qf2;
      short8 ak = *reinterpret_cast<const short8*>(&Ks[(tt * 32 + lid) * 24 + hi * 8]);
      float16 S = __builtin_amdgcn_mfma_f32_32x32x16_bf16(ak, bq, rwC, 0, 0, 0);
      // P = exp2(S); C reg r -> key row (r&3)+8*(r>>2)+4hi; thanks to the V
      // column swap, B-frag #1 = e[0..7], #2 = e[8..15] — lane-local.
      float e[16];
#pragma unroll
      for (int i = 0; i < 16; ++i) e[i] = fast_exp2(S[i]);
      uint4 b1u = make_uint4(pack_bf16(e[0], e[1]), pack_bf16(e[2], e[3]),
                             pack_bf16(e[4], e[5]), pack_bf16(e[6], e[7]));
      uint4 b2u = make_uint4(pack_bf16(e[8], e[9]), pack_bf16(e[10], e[11]),
                             pack_bf16(e[12], e[13]), pack_bf16(e[14], e[15]));
      short8 bp1 = *reinterpret_cast<short8*>(&b1u);
      short8 bp2 = *reinterpret_cast<short8*>(&b2u);
      short8 av1 = *reinterpret_cast<const short8*>(
          &Vs[(lid & 15) * 264 + tt * 32 + hi * 8]);
      short8 av2 = *reinterpret_cast<const short8*>(
          &Vs[(lid & 15) * 264 + tt * 32 + 16 + hi * 8]);
      O = __builtin_amdgcn_mfma_f32_32x32x16_bf16(av1, bp1, O, 0, 0, 0);
      O = __builtin_amdgcn_mfma_f32_32x32x16_bf16(av2, bp2, O, 0, 0, 0);
    }
  }

  // epilogue: normalize by ones-row sum (O reg 6 = row 10, hi=0 lanes), pool
  float lsum = __shfl(O[6], lid);
  float inv = 1.f / lsum;
  int nglob = qt * 128 + qrow;
  int f0 = nglob * 10;
  int c0 = f0 >> 10, c1 = (f0 + 9) >> 10;
  float s0 = 0.f, s1 = 0.f;
  if (!hi) {
#pragma unroll
    for (int r = 0; r < 4; ++r) {   // rows 0..3 = dims 0..3
      float v = O[r] * inv;
      if (((f0 + r) >> 10) == c0) s0 += v; else s1 += v;
    }
#pragma unroll
    for (int r = 4; r < 6; ++r) {   // rows 8,9 = dims 8,9
      int d = r + 4;
      float v = O[r] * inv;
      if (((f0 + d) >> 10) == c0) s0 += v; else s1 += v;
    }
  } else {
#pragma unroll
    for (int r = 0; r < 4; ++r) {   // rows 4..7 = dims 4..7
      int d = r + 4;
      float v = O[r] * inv;
      if (((f0 + d) >> 10) == c0) s0 += v; else s1 += v;
    }
  }
  atomicAdd(&poolL[c0], s0);
  if (c1 != c0) atomicAdd(&poolL[c1], s1);
  __syncthreads();
  if (t < 10) atomicAdd(&pooledA[b * 40 + hd * 10 + t], poolL[t]);
}

// ---------------- final: Sstat assembly + convo-pool matvec + attno + fc ----
__global__ __launch_bounds__(128) void final_kernel(
    const float* __restrict__ sstatP, const float* __restrict__ pooledA,
    const float* __restrict__ h, const float* __restrict__ chanS,
    const float* __restrict__ chanS2, const float* __restrict__ bn_g,
    const float* __restrict__ bn_b,
    const float* __restrict__ convo_w, const float* __restrict__ convo_b,
    const float* __restrict__ attno_w, const float* __restrict__ attno_b,
    const float* __restrict__ fc_w, const float* __restrict__ fc_b,
    float* __restrict__ out) {
  int b = blockIdx.x;
  int t = threadIdx.x;
  __shared__ float Sl[576];
  __shared__ float pooled[128];
  __shared__ float pa[40];
  if (t < 64) {
    int ci = t;
    float mu = chanS[ci] * (1.f / 16384.f);
    float var = chanS2[ci] * (1.f / 16384.f) - mu * mu;
    float sc = bn_g[ci] * rsqrtf(var + 1e-5f);
    float sh = bn_b[ci] - mu * sc;
    const float* hp = h + (size_t)(b * 64 + ci) * 1024;
    float h00 = fmaxf(0.f, hp[0] * sc + sh);
    float h0c = fmaxf(0.f, hp[31] * sc + sh);
    float hr0 = fmaxf(0.f, hp[992] * sc + sh);
    float hrc = fmaxf(0.f, hp[1023] * sc + sh);
    const float* sp = sstatP + (size_t)(b * 64 + ci) * 5;
    float T = sp[0], R0 = sp[1], R31 = sp[2], C0 = sp[3], C31 = sp[4];
    float xr[3] = {R31, 0.f, R0};
    float xc[3] = {C31, 0.f, C0};
    float corner[3][3] = {{hrc, 0.f, hr0}, {0.f, 0.f, 0.f}, {h0c, 0.f, h00}};
#pragma unroll
    for (int dy = 0; dy < 3; ++dy)
#pragma unroll
      for (int dx = 0; dx < 3; ++dx)
        Sl[ci * 9 + dy * 3 + dx] = T - xr[dy] - xc[dx] + corner[dy][dx];
  }
  if (t < 40) pa[t] = pooledA[b * 40 + t] * (1.f / 1024.f);
  __syncthreads();
  if (t < 88) {
    const float4* wr = reinterpret_cast<const float4*>(convo_w + t * 576);
    float acc = 0.f;
    for (int j = 0; j < 144; ++j) {
      float4 v = wr[j];
      acc += v.x * Sl[j * 4] + v.y * Sl[j * 4 + 1] + v.z * Sl[j * 4 + 2] + v.w * Sl[j * 4 + 3];
    }
    pooled[t] = convo_b[t] + acc * (1.f / 1024.f);
  } else if (t < 128) {
    int co = t - 88;
    const float4* wr = reinterpret_cast<const float4*>(attno_w + co * 40);
    float acc = attno_b[co];
    for (int j = 0; j < 10; ++j) {
      float4 v = wr[j];
      acc += v.x * pa[j * 4] + v.y * pa[j * 4 + 1] + v.z * pa[j * 4 + 2] + v.w * pa[j * 4 + 3];
    }
    pooled[88 + co] = acc;
  }
  __syncthreads();
  if (t < 100) {
    const float4* fr = reinterpret_cast<const float4*>(fc_w + t * 128);
    float acc = fc_b[t];
    for (int j = 0; j < 32; ++j) {
      float4 v = fr[j];
      acc += v.x * pooled[j * 4] + v.y * pooled[j * 4 + 1] + v.z * pooled[j * 4 + 2] + v.w * pooled[j * 4 + 3];
    }
    out[b * 100 + t] = acc;
  }
}

extern "C" void kernel_launch(void* const* d_in, const int* in_sizes, int n_in,
                              void* d_out, int out_size, void* d_ws, size_t ws_size,
                              hipStream_t stream) {
  const float* x         = (const float*)d_in[0];
  const float* conv1_w   = (const float*)d_in[1];
  const float* conv1_b   = (const float*)d_in[2];
  const float* bn1_g     = (const float*)d_in[3];
  const float* bn1_b     = (const float*)d_in[4];
  const float* convo_w   = (const float*)d_in[5];
  const float* convo_b   = (const float*)d_in[6];
  const float* qkv_w     = (const float*)d_in[7];
  const float* qkv_b     = (const float*)d_in[8];
  const float* attno_w   = (const float*)d_in[9];
  const float* attno_b   = (const float*)d_in[10];
  const float* key_rel_h = (const float*)d_in[11];
  const float* key_rel_w = (const float*)d_in[12];
  const float* fc_w      = (const float*)d_in[13];
  const float* fc_b      = (const float*)d_in[14];

  float* ws      = (float*)d_ws;
  float* h       = ws + WS_H;
  float* qkvb    = ws + WS_QKV;
  float* chanS   = ws + WS_ACC;
  float* chanS2  = chanS + 64;
  float* sstatP  = chanS2 + 64;
  float* pooledA = sstatP + 5120;

  hipMemsetAsync(chanS, 0, ACC_BYTES, stream);
  conv1_kernel<<<512, 256, 0, stream>>>(x, conv1_w, conv1_b, h, chanS, chanS2);
  qkv_kernel3<<<512, 256, 0, stream>>>(h, chanS, chanS2, bn1_g, bn1_b,
                                       qkv_w, qkv_b, qkvb, sstatP);
  attn_mfma_kernel<<<512, 256, 0, stream>>>(qkvb, key_rel_w, key_rel_h, pooledA);
  final_kernel<<<16, 128, 0, stream>>>(sstatP, pooledA, h, chanS, chanS2,
                                       bn1_g, bn1_b, convo_w, convo_b,
                                       attno_w, attno_b, fc_w, fc_b, (float*)d_out);
}

// Round 9
// 193.371 us; speedup vs baseline: 1.4607x; 1.4607x over previous
//
#include <hip/hip_runtime.h>
#include <hip/hip_bf16.h>

// SimpleAugmentedCNN forward, B=16, H=W=32, NH=4, DKH=DVH=10.
// 5 dispatches: memset(acc) -> conv1(LDS-staged, +BN-stat atomics) ->
// qkv3(BN+relu+sstat+1x1) -> attn_mfma -> final.
// attn_mfma: 32x32x16 bf16; S^T=K.Q^T (C col=query, row=key); rw folded as
// C-init; rh via spare dim10 from packed regs; softmax denom via ones-row in
// V; P feeds PV MFMA *lane-locally* via V key-slot bit2<->3 swap (no LDS
// round-trip, no shuffles); avg-pool fused with atomics.
// R9 fix vs R8: __launch_bounds__(256,4) capped VGPR at 64 -> massive scratch
// spills (WRITE_SIZE 197MB, FETCH 120MB). Back to (256,2): VGPR free to ~160,
// 2 waves/SIMD, zero spill — spills cost far more than occupancy buys.

#define WS_H     0                      // 16*64*1024   = 1048576 floats
#define WS_QKV   1048576                // 16*120*1024  = 1966080
#define WS_ACC   3014656                // chanS 64 | chanS2 64 | sstatP 5120 | pooledA 640
#define ACC_BYTES ((64 + 64 + 5120 + 640) * 4)

typedef __attribute__((ext_vector_type(8))) short short8;
typedef __attribute__((ext_vector_type(16))) float float16;

__device__ __forceinline__ float fast_exp2(float x) {
#if __has_builtin(__builtin_amdgcn_exp2f)
  return __builtin_amdgcn_exp2f(x);
#else
  return exp2f(x);
#endif
}
__device__ __forceinline__ short f2bf(float x) {
  __hip_bfloat16 h(x);                 // RNE
  return *reinterpret_cast<short*>(&h);
}
__device__ __forceinline__ float bf2f(short s) {
  return __uint_as_float(((unsigned)(unsigned short)s) << 16);
}
__device__ __forceinline__ unsigned pack_bf16(float a, float b) {
  return (__float_as_uint(a) >> 16) | (__float_as_uint(b) & 0xFFFF0000u);
}

// ---------------- conv1: 3->64 3x3 SAME, LDS-staged x, 2 co/block -----------
__global__ __launch_bounds__(256) void conv1_kernel(
    const float* __restrict__ x, const float* __restrict__ w,
    const float* __restrict__ bias, float* __restrict__ h,
    float* __restrict__ chanS, float* __restrict__ chanS2) {
  int b = blockIdx.x >> 5, cg = blockIdx.x & 31;
  int co0 = cg * 2;
  int t = threadIdx.x;
  __shared__ float xs[3072];
  const float4* xg = reinterpret_cast<const float4*>(x + b * 3072);
  float4* xsv = reinterpret_cast<float4*>(xs);
  for (int i = t; i < 768; i += 256) xsv[i] = xg[i];

  typedef const __attribute__((address_space(4))) float* cfp;
  cfp wc = (cfp)(size_t)w;
  float wr0[27], wr1[27];
#pragma unroll
  for (int i = 0; i < 27; ++i) { wr0[i] = wc[co0 * 27 + i]; wr1[i] = wc[(co0 + 1) * 27 + i]; }
  float bv0 = bias[co0], bv1 = bias[co0 + 1];
  __syncthreads();

  int row = t >> 3, col0 = (t & 7) * 4;
  float acc0[4] = {bv0, bv0, bv0, bv0};
  float acc1[4] = {bv1, bv1, bv1, bv1};
#pragma unroll
  for (int ci = 0; ci < 3; ++ci) {
#pragma unroll
    for (int dy = 0; dy < 3; ++dy) {
      int sr = row + dy - 1;
      if (sr < 0 || sr > 31) continue;
      const float* xr = &xs[ci * 1024 + sr * 32];
      float xv[6];
#pragma unroll
      for (int j = 0; j < 6; ++j) {
        int c = col0 - 1 + j;
        xv[j] = (c >= 0 && c < 32) ? xr[c] : 0.f;
      }
#pragma unroll
      for (int dx = 0; dx < 3; ++dx) {
        float w0 = wr0[ci * 9 + dy * 3 + dx], w1 = wr1[ci * 9 + dy * 3 + dx];
#pragma unroll
        for (int k = 0; k < 4; ++k) {
          acc0[k] += w0 * xv[k + dx];
          acc1[k] += w1 * xv[k + dx];
        }
      }
    }
  }
  *reinterpret_cast<float4*>(&h[(size_t)(b * 64 + co0) * 1024 + t * 4]) =
      make_float4(acc0[0], acc0[1], acc0[2], acc0[3]);
  *reinterpret_cast<float4*>(&h[(size_t)(b * 64 + co0 + 1) * 1024 + t * 4]) =
      make_float4(acc1[0], acc1[1], acc1[2], acc1[3]);

  float s10 = acc0[0] + acc0[1] + acc0[2] + acc0[3];
  float s20 = acc0[0]*acc0[0] + acc0[1]*acc0[1] + acc0[2]*acc0[2] + acc0[3]*acc0[3];
  float s11 = acc1[0] + acc1[1] + acc1[2] + acc1[3];
  float s21 = acc1[0]*acc1[0] + acc1[1]*acc1[1] + acc1[2]*acc1[2] + acc1[3]*acc1[3];
#pragma unroll
  for (int off = 32; off > 0; off >>= 1) {
    s10 += __shfl_down(s10, off);
    s20 += __shfl_down(s20, off);
    s11 += __shfl_down(s11, off);
    s21 += __shfl_down(s21, off);
  }
  if ((t & 63) == 0) {
    atomicAdd(&chanS[co0], s10);
    atomicAdd(&chanS2[co0], s20);
    atomicAdd(&chanS[co0 + 1], s11);
    atomicAdd(&chanS2[co0 + 1], s21);
  }
}

// ---------------- qkv3: BN-apply + relu + sstat partials + qkv 1x1 ----------
__global__ __launch_bounds__(256) void qkv_kernel3(
    const float* __restrict__ h, const float* __restrict__ chanS,
    const float* __restrict__ chanS2, const float* __restrict__ bn_g,
    const float* __restrict__ bn_b, const float* __restrict__ qw,
    const float* __restrict__ qb, float* __restrict__ qkv,
    float* __restrict__ sstatP) {
  int bid = blockIdx.x;
  int half = bid & 1, ck = (bid >> 1) & 15, b = bid >> 5;
  int t = threadIdx.x;
  __shared__ float ssc[64], ssh[64];
  __shared__ float hs[64][65];
  if (t < 64) {
    float mu = chanS[t] * (1.f / 16384.f);
    float var = chanS2[t] * (1.f / 16384.f) - mu * mu;
    float sc = bn_g[t] * rsqrtf(var + 1e-5f);
    ssc[t] = sc;
    ssh[t] = bn_b[t] - mu * sc;
  }
  __syncthreads();
  int pos = t & 63, grp = t >> 6;
#pragma unroll
  for (int r = 0; r < 16; ++r) {
    int ci = r * 4 + grp;
    float v = h[(size_t)(b * 64 + ci) * 1024 + ck * 64 + pos];
    hs[ci][pos] = fmaxf(0.f, v * ssc[ci] + ssh[ci]);
  }
  __syncthreads();
  if (half == 0 && t < 128) {
    int ci = t >> 1, rl = t & 1;
    int row = ck * 2 + rl;
    const float* hp = &hs[ci][rl * 32];
    float T = 0.f;
#pragma unroll
    for (int k = 0; k < 32; ++k) T += hp[k];
    float* sp = sstatP + (size_t)(b * 64 + ci) * 5;
    atomicAdd(sp + 0, T);
    if (row == 0) atomicAdd(sp + 1, T);
    if (row == 31) atomicAdd(sp + 2, T);
    atomicAdd(sp + 3, hp[0]);
    atomicAdd(sp + 4, hp[31]);
  }
  int co0 = half * 60 + grp * 15;
  float acc[15];
#pragma unroll
  for (int j = 0; j < 15; ++j) acc[j] = 0.f;
  typedef const __attribute__((address_space(4))) float* cfp;
  cfp qwc = (cfp)(size_t)qw;
  for (int ci = 0; ci < 64; ++ci) {
    float hv = hs[ci][pos];
#pragma unroll
    for (int j = 0; j < 15; ++j) acc[j] += qwc[(co0 + j) * 64 + ci] * hv;
  }
#pragma unroll
  for (int j = 0; j < 15; ++j)
    qkv[(size_t)(b * 120 + co0 + j) * 1024 + ck * 64 + pos] = acc[j] + qb[co0 + j];
}

// ---------------- MFMA attention, lane-local P, fused pool ------------------
// grid 512 = b*32 + hd*8 + qt; block 256 = 4 waves; wave = 32 queries x 1024 keys.
// V staged with key-slot bits 2<->3 swapped so the QK^T C-regs ARE the PV
// B-frags (e[0..7] -> MFMA#1, e[8..15] -> MFMA#2), no cross-lane movement.
__global__ __launch_bounds__(256, 2) void attn_mfma_kernel(
    const float* __restrict__ qkv, const float* __restrict__ relw,
    const float* __restrict__ relh, float* __restrict__ pooledA) {
  int bid = blockIdx.x;
  int qt = bid & 7, hd = (bid >> 3) & 3, b = bid >> 5;
  int t = threadIdx.x;
  int lane = t & 63, w = t >> 6, lid = lane & 31, hi = lane >> 5;

  __shared__ __align__(16) short Ks[256 * 24];   // [key][24] bf16 (d10=1, 11..15=0)
  __shared__ __align__(16) short Vs[16 * 264];   // [dim][264] bf16 (row10=1)
  __shared__ float poolL[16];

  short* Qs = Ks;                     // overlay [128][16] (setup only)
  float* RwL = (float*)Vs;            // [63][10] fp32 (setup only)
  float* RhL = RwL + 630;

  if (t < 16) poolL[t] = 0.f;
  const float QS2 = 0.31622776601683794f * 1.4426950408889634f;  // dkh^-0.5 * log2e
  const float* qg = qkv + (size_t)(b * 120 + hd * 10) * 1024 + qt * 128;
  for (int i = t; i < 630; i += 256) {
    RwL[i] = relw[i];
    RhL[i] = relh[i];
  }
  for (int i = t; i < 1280; i += 256) {
    int q = i & 127, d = i >> 7;
    Qs[q * 16 + d] = f2bf(qg[d * 1024 + q] * QS2);
  }
  __syncthreads();

  int qrow = w * 32 + lid;            // block-local query
  float qfv[10];
#pragma unroll
  for (int d = 0; d < 10; ++d) qfv[d] = bf2f(Qs[qrow * 16 + d]);

  // rw C-init: rwC[r] = dot(q, Rw[31 + y'(r) - y(q)]), y(q)=lid, y'(r)=C-row
  float16 rwC;
#pragma unroll
  for (int r = 0; r < 16; ++r) {
    int yp = (r & 3) + 8 * (r >> 2) + 4 * hi;
    const float* rp = &RwL[(31 + yp - lid) * 10];
    float s = 0.f;
#pragma unroll
    for (int d = 0; d < 10; ++d) s += qfv[d] * rp[d];
    rwC[r] = s;
  }
  // rh for all 32 tiles (x' = 0..31), packed bf16 pairs in 16 regs
  int xn = qt * 4 + w;
  unsigned rhp[16];
#pragma unroll
  for (int j = 0; j < 16; ++j) {
    const float* rpa = &RhL[(31 + 2 * j - xn) * 10];
    const float* rpb = &RhL[(31 + 2 * j + 1 - xn) * 10];
    float sa = 0.f, sb = 0.f;
#pragma unroll
    for (int d = 0; d < 10; ++d) { sa += qfv[d] * rpa[d]; sb += qfv[d] * rpb[d]; }
    rhp[j] = pack_bf16(sa, sb);
  }
  // Q B-frag (col=q, k=dims)
  short8 qf = *reinterpret_cast<const short8*>(&Qs[qrow * 16 + hi * 8]);
  short qf2 = qf[2];
  if (hi) { qf[3] = 0; qf[4] = 0; qf[5] = 0; qf[6] = 0; qf[7] = 0; }

  float16 O;
#pragma unroll
  for (int i = 0; i < 16; ++i) O[i] = 0.f;

  const float* kg = qkv + (size_t)(b * 120 + 40 + hd * 10) * 1024;
  const float* vg = kg + 40 * 1024;

  for (int p = 0; p < 4; ++p) {
    __syncthreads();   // overlays consumed (p=0) / prev pass reads done
    for (int i = t; i < 2560; i += 256) {
      int d = i >> 8, key = i & 255;
      Ks[key * 24 + d] = f2bf(kg[d * 1024 + p * 256 + key]);
      // V column: swap bits 2<->3 of within-32 key index
      int kc = (key & 0xF3) | ((key & 4) << 1) | ((key & 8) >> 1);
      Vs[d * 264 + kc] = f2bf(vg[d * 1024 + p * 256 + key]);
    }
    Ks[t * 24 + 10] = (short)0x3F80;   // K dim10 = 1.0 (rh carrier)
#pragma unroll
    for (int d2 = 11; d2 < 16; ++d2) Ks[t * 24 + d2] = 0;  // NaN guard
    Vs[10 * 264 + t] = (short)0x3F80;  // ones-row (denominator)
    __syncthreads();

#pragma unroll
    for (int tt = 0; tt < 8; ++tt) {
      int Tl = p * 8 + tt;
      unsigned rhw = rhp[Tl >> 1];
      short rhu = (short)((Tl & 1) ? (rhw >> 16) : (rhw & 0xFFFFu));
      short8 bq = qf;
      bq[2] = hi ? rhu : qf2;
      short8 ak = *reinterpret_cast<const short8*>(&Ks[(tt * 32 + lid) * 24 + hi * 8]);
      float16 S = __builtin_amdgcn_mfma_f32_32x32x16_bf16(ak, bq, rwC, 0, 0, 0);
      // P = exp2(S); C reg r -> key row (r&3)+8*(r>>2)+4hi; thanks to the V
      // column swap, B-frag #1 = e[0..7], #2 = e[8..15] — lane-local.
      float e[16];
#pragma unroll
      for (int i = 0; i < 16; ++i) e[i] = fast_exp2(S[i]);
      uint4 b1u = make_uint4(pack_bf16(e[0], e[1]), pack_bf16(e[2], e[3]),
                             pack_bf16(e[4], e[5]), pack_bf16(e[6], e[7]));
      uint4 b2u = make_uint4(pack_bf16(e[8], e[9]), pack_bf16(e[10], e[11]),
                             pack_bf16(e[12], e[13]), pack_bf16(e[14], e[15]));
      short8 bp1 = *reinterpret_cast<short8*>(&b1u);
      short8 bp2 = *reinterpret_cast<short8*>(&b2u);
      short8 av1 = *reinterpret_cast<const short8*>(
          &Vs[(lid & 15) * 264 + tt * 32 + hi * 8]);
      short8 av2 = *reinterpret_cast<const short8*>(
          &Vs[(lid & 15) * 264 + tt * 32 + 16 + hi * 8]);
      O = __builtin_amdgcn_mfma_f32_32x32x16_bf16(av1, bp1, O, 0, 0, 0);
      O = __builtin_amdgcn_mfma_f32_32x32x16_bf16(av2, bp2, O, 0, 0, 0);
    }
  }

  // epilogue: normalize by ones-row sum (O reg 6 = row 10, hi=0 lanes), pool
  float lsum = __shfl(O[6], lid);
  float inv = 1.f / lsum;
  int nglob = qt * 128 + qrow;
  int f0 = nglob * 10;
  int c0 = f0 >> 10, c1 = (f0 + 9) >> 10;
  float s0 = 0.f, s1 = 0.f;
  if (!hi) {
#pragma unroll
    for (int r = 0; r < 4; ++r) {   // rows 0..3 = dims 0..3
      float v = O[r] * inv;
      if (((f0 + r) >> 10) == c0) s0 += v; else s1 += v;
    }
#pragma unroll
    for (int r = 4; r < 6; ++r) {   // rows 8,9 = dims 8,9
      int d = r + 4;
      float v = O[r] * inv;
      if (((f0 + d) >> 10) == c0) s0 += v; else s1 += v;
    }
  } else {
#pragma unroll
    for (int r = 0; r < 4; ++r) {   // rows 4..7 = dims 4..7
      int d = r + 4;
      float v = O[r] * inv;
      if (((f0 + d) >> 10) == c0) s0 += v; else s1 += v;
    }
  }
  atomicAdd(&poolL[c0], s0);
  if (c1 != c0) atomicAdd(&poolL[c1], s1);
  __syncthreads();
  if (t < 10) atomicAdd(&pooledA[b * 40 + hd * 10 + t], poolL[t]);
}

// ---------------- final: Sstat assembly + convo-pool matvec + attno + fc ----
__global__ __launch_bounds__(128) void final_kernel(
    const float* __restrict__ sstatP, const float* __restrict__ pooledA,
    const float* __restrict__ h, const float* __restrict__ chanS,
    const float* __restrict__ chanS2, const float* __restrict__ bn_g,
    const float* __restrict__ bn_b,
    const float* __restrict__ convo_w, const float* __restrict__ convo_b,
    const float* __restrict__ attno_w, const float* __restrict__ attno_b,
    const float* __restrict__ fc_w, const float* __restrict__ fc_b,
    float* __restrict__ out) {
  int b = blockIdx.x;
  int t = threadIdx.x;
  __shared__ float Sl[576];
  __shared__ float pooled[128];
  __shared__ float pa[40];
  if (t < 64) {
    int ci = t;
    float mu = chanS[ci] * (1.f / 16384.f);
    float var = chanS2[ci] * (1.f / 16384.f) - mu * mu;
    float sc = bn_g[ci] * rsqrtf(var + 1e-5f);
    float sh = bn_b[ci] - mu * sc;
    const float* hp = h + (size_t)(b * 64 + ci) * 1024;
    float h00 = fmaxf(0.f, hp[0] * sc + sh);
    float h0c = fmaxf(0.f, hp[31] * sc + sh);
    float hr0 = fmaxf(0.f, hp[992] * sc + sh);
    float hrc = fmaxf(0.f, hp[1023] * sc + sh);
    const float* sp = sstatP + (size_t)(b * 64 + ci) * 5;
    float T = sp[0], R0 = sp[1], R31 = sp[2], C0 = sp[3], C31 = sp[4];
    float xr[3] = {R31, 0.f, R0};
    float xc[3] = {C31, 0.f, C0};
    float corner[3][3] = {{hrc, 0.f, hr0}, {0.f, 0.f, 0.f}, {h0c, 0.f, h00}};
#pragma unroll
    for (int dy = 0; dy < 3; ++dy)
#pragma unroll
      for (int dx = 0; dx < 3; ++dx)
        Sl[ci * 9 + dy * 3 + dx] = T - xr[dy] - xc[dx] + corner[dy][dx];
  }
  if (t < 40) pa[t] = pooledA[b * 40 + t] * (1.f / 1024.f);
  __syncthreads();
  if (t < 88) {
    const float4* wr = reinterpret_cast<const float4*>(convo_w + t * 576);
    float acc = 0.f;
    for (int j = 0; j < 144; ++j) {
      float4 v = wr[j];
      acc += v.x * Sl[j * 4] + v.y * Sl[j * 4 + 1] + v.z * Sl[j * 4 + 2] + v.w * Sl[j * 4 + 3];
    }
    pooled[t] = convo_b[t] + acc * (1.f / 1024.f);
  } else if (t < 128) {
    int co = t - 88;
    const float4* wr = reinterpret_cast<const float4*>(attno_w + co * 40);
    float acc = attno_b[co];
    for (int j = 0; j < 10; ++j) {
      float4 v = wr[j];
      acc += v.x * pa[j * 4] + v.y * pa[j * 4 + 1] + v.z * pa[j * 4 + 2] + v.w * pa[j * 4 + 3];
    }
    pooled[88 + co] = acc;
  }
  __syncthreads();
  if (t < 100) {
    const float4* fr = reinterpret_cast<const float4*>(fc_w + t * 128);
    float acc = fc_b[t];
    for (int j = 0; j < 32; ++j) {
      float4 v = fr[j];
      acc += v.x * pooled[j * 4] + v.y * pooled[j * 4 + 1] + v.z * pooled[j * 4 + 2] + v.w * pooled[j * 4 + 3];
    }
    out[b * 100 + t] = acc;
  }
}

extern "C" void kernel_launch(void* const* d_in, const int* in_sizes, int n_in,
                              void* d_out, int out_size, void* d_ws, size_t ws_size,
                              hipStream_t stream) {
  const float* x         = (const float*)d_in[0];
  const float* conv1_w   = (const float*)d_in[1];
  const float* conv1_b   = (const float*)d_in[2];
  const float* bn1_g     = (const float*)d_in[3];
  const float* bn1_b     = (const float*)d_in[4];
  const float* convo_w   = (const float*)d_in[5];
  const float* convo_b   = (const float*)d_in[6];
  const float* qkv_w     = (const float*)d_in[7];
  const float* qkv_b     = (const float*)d_in[8];
  const float* attno_w   = (const float*)d_in[9];
  const float* attno_b   = (const float*)d_in[10];
  const float* key_rel_h = (const float*)d_in[11];
  const float* key_rel_w = (const float*)d_in[12];
  const float* fc_w      = (const float*)d_in[13];
  const float* fc_b      = (const float*)d_in[14];

  float* ws      = (float*)d_ws;
  float* h       = ws + WS_H;
  float* qkvb    = ws + WS_QKV;
  float* chanS   = ws + WS_ACC;
  float* chanS2  = chanS + 64;
  float* sstatP  = chanS2 + 64;
  float* pooledA = sstatP + 5120;

  hipMemsetAsync(chanS, 0, ACC_BYTES, stream);
  conv1_kernel<<<512, 256, 0, stream>>>(x, conv1_w, conv1_b, h, chanS, chanS2);
  qkv_kernel3<<<512, 256, 0, stream>>>(h, chanS, chanS2, bn1_g, bn1_b,
                                       qkv_w, qkv_b, qkvb, sstatP);
  attn_mfma_kernel<<<512, 256, 0, stream>>>(qkvb, key_rel_w, key_rel_h, pooledA);
  final_kernel<<<16, 128, 0, stream>>>(sstatP, pooledA, h, chanS, chanS2,
                                       bn1_g, bn1_b, convo_w, convo_b,
                                       attno_w, attno_b, fc_w, fc_b, (float*)d_out);
}

// Round 10
// 163.791 us; speedup vs baseline: 1.7245x; 1.1806x over previous
//
#include <hip/hip_runtime.h>
#include <hip/hip_bf16.h>

// SimpleAugmentedCNN forward, B=16, H=W=32, NH=4, DKH=DVH=10.
// 4 dispatches (no memset, no global atomics — slot-partials everywhere):
// conv1(LDS-staged, BN-stat partials) -> qkv3(BN+relu+sstat-partials+1x1) ->
// attn_mfma(pool partials) -> final(sums all partials + matvecs).
// attn_mfma: 32x32x16 bf16; S^T=K.Q^T (C col=query, row=key); rw folded as
// C-init; rh via spare dim10; denom via ones-row in V; P feeds PV MFMA
// lane-locally via V key-slot bit2<->3 swap. Rel tables padded to 12 f/row
// (float4 reads: 144 LDS ops vs 480 scalar). bf16 via truncation (1 inst).
// R8 lesson kept: __launch_bounds__(256,2) — (256,4) caused scratch spills.

#define WS_H      0                      // 16*64*1024   = 1048576 floats
#define WS_QKV    1048576                // 16*120*1024  = 1966080
#define WS_CHANS  3014656                // chanSP [64][16] = 1024
#define WS_CHANS2 3015680                // chanS2P [64][16] = 1024
#define WS_SSTATP 3016704                // [16][64][16ck][5] = 81920
#define WS_POOLP  3098624                // [16][4][8][16] = 8192

typedef __attribute__((ext_vector_type(8))) short short8;
typedef __attribute__((ext_vector_type(16))) float float16;

__device__ __forceinline__ float fast_exp2(float x) {
#if __has_builtin(__builtin_amdgcn_exp2f)
  return __builtin_amdgcn_exp2f(x);
#else
  return exp2f(x);
#endif
}
// truncating f32->bf16 (1 inst; error budget has 3 decades of headroom)
__device__ __forceinline__ short f2bf(float x) {
  return (short)(__float_as_uint(x) >> 16);
}
__device__ __forceinline__ float bf2f(short s) {
  return __uint_as_float(((unsigned)(unsigned short)s) << 16);
}
__device__ __forceinline__ unsigned pack_bf16(float a, float b) {
  return (__float_as_uint(a) >> 16) | (__float_as_uint(b) & 0xFFFF0000u);
}

// ---------------- conv1: 3->64 3x3 SAME, LDS-staged x, 2 co/block -----------
// grid 512 = b*32 + cg. Writes BN-stat partials (no atomics, no zero-init).
__global__ __launch_bounds__(256) void conv1_kernel(
    const float* __restrict__ x, const float* __restrict__ w,
    const float* __restrict__ bias, float* __restrict__ h,
    float* __restrict__ chanSP, float* __restrict__ chanS2P) {
  int b = blockIdx.x >> 5, cg = blockIdx.x & 31;
  int co0 = cg * 2;
  int t = threadIdx.x;
  __shared__ float xs[3072];
  __shared__ float red[4][4];
  const float4* xg = reinterpret_cast<const float4*>(x + b * 3072);
  float4* xsv = reinterpret_cast<float4*>(xs);
  for (int i = t; i < 768; i += 256) xsv[i] = xg[i];

  typedef const __attribute__((address_space(4))) float* cfp;
  cfp wc = (cfp)(size_t)w;
  float wr0[27], wr1[27];
#pragma unroll
  for (int i = 0; i < 27; ++i) { wr0[i] = wc[co0 * 27 + i]; wr1[i] = wc[(co0 + 1) * 27 + i]; }
  float bv0 = bias[co0], bv1 = bias[co0 + 1];
  __syncthreads();

  int row = t >> 3, col0 = (t & 7) * 4;
  float acc0[4] = {bv0, bv0, bv0, bv0};
  float acc1[4] = {bv1, bv1, bv1, bv1};
#pragma unroll
  for (int ci = 0; ci < 3; ++ci) {
#pragma unroll
    for (int dy = 0; dy < 3; ++dy) {
      int sr = row + dy - 1;
      if (sr < 0 || sr > 31) continue;
      const float* xr = &xs[ci * 1024 + sr * 32];
      float xv[6];
#pragma unroll
      for (int j = 0; j < 6; ++j) {
        int c = col0 - 1 + j;
        xv[j] = (c >= 0 && c < 32) ? xr[c] : 0.f;
      }
#pragma unroll
      for (int dx = 0; dx < 3; ++dx) {
        float w0 = wr0[ci * 9 + dy * 3 + dx], w1 = wr1[ci * 9 + dy * 3 + dx];
#pragma unroll
        for (int k = 0; k < 4; ++k) {
          acc0[k] += w0 * xv[k + dx];
          acc1[k] += w1 * xv[k + dx];
        }
      }
    }
  }
  *reinterpret_cast<float4*>(&h[(size_t)(b * 64 + co0) * 1024 + t * 4]) =
      make_float4(acc0[0], acc0[1], acc0[2], acc0[3]);
  *reinterpret_cast<float4*>(&h[(size_t)(b * 64 + co0 + 1) * 1024 + t * 4]) =
      make_float4(acc1[0], acc1[1], acc1[2], acc1[3]);

  float s10 = acc0[0] + acc0[1] + acc0[2] + acc0[3];
  float s20 = acc0[0]*acc0[0] + acc0[1]*acc0[1] + acc0[2]*acc0[2] + acc0[3]*acc0[3];
  float s11 = acc1[0] + acc1[1] + acc1[2] + acc1[3];
  float s21 = acc1[0]*acc1[0] + acc1[1]*acc1[1] + acc1[2]*acc1[2] + acc1[3]*acc1[3];
#pragma unroll
  for (int off = 32; off > 0; off >>= 1) {
    s10 += __shfl_down(s10, off);
    s20 += __shfl_down(s20, off);
    s11 += __shfl_down(s11, off);
    s21 += __shfl_down(s21, off);
  }
  int wv = t >> 6;
  if ((t & 63) == 0) {
    red[wv][0] = s10; red[wv][1] = s20; red[wv][2] = s11; red[wv][3] = s21;
  }
  __syncthreads();
  if (t == 0) {
    float a = red[0][0] + red[1][0] + red[2][0] + red[3][0];
    float bq = red[0][1] + red[1][1] + red[2][1] + red[3][1];
    float c = red[0][2] + red[1][2] + red[2][2] + red[3][2];
    float d = red[0][3] + red[1][3] + red[2][3] + red[3][3];
    chanSP[co0 * 16 + b] = a;
    chanS2P[co0 * 16 + b] = bq;
    chanSP[(co0 + 1) * 16 + b] = c;
    chanS2P[(co0 + 1) * 16 + b] = d;
  }
}

// ---------------- qkv3: BN-apply + relu + sstat partials + qkv 1x1 ----------
// grid 512 = b*32 + ck*2 + half. sstat partials: plain stores per (b,ci,ck).
__global__ __launch_bounds__(256) void qkv_kernel3(
    const float* __restrict__ h, const float* __restrict__ chanSP,
    const float* __restrict__ chanS2P, const float* __restrict__ bn_g,
    const float* __restrict__ bn_b, const float* __restrict__ qw,
    const float* __restrict__ qb, float* __restrict__ qkv,
    float* __restrict__ sstatP) {
  int bid = blockIdx.x;
  int half = bid & 1, ck = (bid >> 1) & 15, b = bid >> 5;
  int t = threadIdx.x;
  __shared__ float ssc[64], ssh[64];
  __shared__ float hs[64][65];
  if (t < 64) {
    const float4* p1 = reinterpret_cast<const float4*>(&chanSP[t * 16]);
    const float4* p2 = reinterpret_cast<const float4*>(&chanS2P[t * 16]);
    float4 a0 = p1[0], a1 = p1[1], a2 = p1[2], a3 = p1[3];
    float4 c0 = p2[0], c1 = p2[1], c2 = p2[2], c3 = p2[3];
    float S1 = a0.x+a0.y+a0.z+a0.w + a1.x+a1.y+a1.z+a1.w
             + a2.x+a2.y+a2.z+a2.w + a3.x+a3.y+a3.z+a3.w;
    float S2 = c0.x+c0.y+c0.z+c0.w + c1.x+c1.y+c1.z+c1.w
             + c2.x+c2.y+c2.z+c2.w + c3.x+c3.y+c3.z+c3.w;
    float mu = S1 * (1.f / 16384.f);
    float var = S2 * (1.f / 16384.f) - mu * mu;
    float sc = bn_g[t] * rsqrtf(var + 1e-5f);
    ssc[t] = sc;
    ssh[t] = bn_b[t] - mu * sc;
  }
  __syncthreads();
  int pos = t & 63, grp = t >> 6;
#pragma unroll
  for (int r = 0; r < 16; ++r) {
    int ci = r * 4 + grp;
    float v = h[(size_t)(b * 64 + ci) * 1024 + ck * 64 + pos];
    hs[ci][pos] = fmaxf(0.f, v * ssc[ci] + ssh[ci]);
  }
  __syncthreads();
  if (half == 0 && t < 128) {   // waves 0,1 fully active -> shfl safe
    int ci = t >> 1, rl = t & 1;
    const float* hp = &hs[ci][rl * 32];
    float T = 0.f;
#pragma unroll
    for (int k = 0; k < 32; ++k) T += hp[k];
    float c0v = hp[0], c31v = hp[31];
    float Tp = __shfl_down(T, 1);      // partner row's sum
    float c0p = __shfl_down(c0v, 1);
    float c31p = __shfl_down(c31v, 1);
    if (rl == 0) {
      float* sp = sstatP + ((size_t)(b * 64 + ci) * 16 + ck) * 5;
      sp[0] = T + Tp;                      // total (2 rows)
      sp[1] = (ck == 0) ? T : 0.f;         // row 0
      sp[2] = (ck == 15) ? Tp : 0.f;       // row 31
      sp[3] = c0v + c0p;                   // col 0
      sp[4] = c31v + c31p;                 // col 31
    }
  }
  int co0 = half * 60 + grp * 15;
  float acc[15];
#pragma unroll
  for (int j = 0; j < 15; ++j) acc[j] = 0.f;
  typedef const __attribute__((address_space(4))) float* cfp;
  cfp qwc = (cfp)(size_t)qw;
  for (int ci = 0; ci < 64; ++ci) {
    float hv = hs[ci][pos];
#pragma unroll
    for (int j = 0; j < 15; ++j) acc[j] += qwc[(co0 + j) * 64 + ci] * hv;
  }
#pragma unroll
  for (int j = 0; j < 15; ++j)
    qkv[(size_t)(b * 120 + co0 + j) * 1024 + ck * 64 + pos] = acc[j] + qb[co0 + j];
}

// ---------------- MFMA attention, lane-local P, pool partials ---------------
// grid 512 = b*32 + hd*8 + qt; block 256 = 4 waves; wave = 32 queries x 1024 keys.
__global__ __launch_bounds__(256, 2) void attn_mfma_kernel(
    const float* __restrict__ qkv, const float* __restrict__ relw,
    const float* __restrict__ relh, float* __restrict__ poolP) {
  int bid = blockIdx.x;
  int qt = bid & 7, hd = (bid >> 3) & 3, b = bid >> 5;
  int t = threadIdx.x;
  int lane = t & 63, w = t >> 6, lid = lane & 31, hi = lane >> 5;

  __shared__ __align__(16) short Ks[256 * 24];   // [key][24] bf16 (d10=1, 11..15=0)
  __shared__ __align__(16) short Vs[16 * 264];   // [dim][264] bf16 (row10=1)
  __shared__ float poolL[16];

  short* Qs = Ks;                     // overlay [128][16] (setup only)
  float* RwL = (float*)Vs;            // [63][12] f32 padded rows (setup only)
  float* RhL = RwL + 756;             // 756+756 floats = 6048B < sizeof(Vs)

  if (t < 16) poolL[t] = 0.f;
  const float QS2 = 0.31622776601683794f * 1.4426950408889634f;  // dkh^-0.5 * log2e
  const float* qg = qkv + (size_t)(b * 120 + hd * 10) * 1024 + qt * 128;
  for (int i = t; i < 630; i += 256) {
    int r = i / 10, d = i - r * 10;
    RwL[r * 12 + d] = relw[i];
    RhL[r * 12 + d] = relh[i];
  }
  for (int i = t; i < 1280; i += 256) {
    int q = i & 127, d = i >> 7;
    Qs[q * 16 + d] = f2bf(qg[d * 1024 + q] * QS2);
  }
  __syncthreads();

  int qrow = w * 32 + lid;            // block-local query
  float qfv[10];
#pragma unroll
  for (int d = 0; d < 10; ++d) qfv[d] = bf2f(Qs[qrow * 16 + d]);

  // rw C-init via padded float4 reads (3 LDS ops/row instead of 10)
  float16 rwC;
#pragma unroll
  for (int r = 0; r < 16; ++r) {
    int yp = (r & 3) + 8 * (r >> 2) + 4 * hi;
    const float* rp = &RwL[(31 + yp - lid) * 12];
    float4 a = *reinterpret_cast<const float4*>(rp);
    float4 bb = *reinterpret_cast<const float4*>(rp + 4);
    float2 cc = *reinterpret_cast<const float2*>(rp + 8);
    rwC[r] = qfv[0] * a.x + qfv[1] * a.y + qfv[2] * a.z + qfv[3] * a.w
           + qfv[4] * bb.x + qfv[5] * bb.y + qfv[6] * bb.z + qfv[7] * bb.w
           + qfv[8] * cc.x + qfv[9] * cc.y;
  }
  // rh for all 32 tiles, packed bf16 pairs
  int xn = qt * 4 + w;
  unsigned rhp[16];
#pragma unroll
  for (int j = 0; j < 16; ++j) {
    float s2[2];
#pragma unroll
    for (int u = 0; u < 2; ++u) {
      const float* rp = &RhL[(31 + 2 * j + u - xn) * 12];
      float4 a = *reinterpret_cast<const float4*>(rp);
      float4 bb = *reinterpret_cast<const float4*>(rp + 4);
      float2 cc = *reinterpret_cast<const float2*>(rp + 8);
      s2[u] = qfv[0] * a.x + qfv[1] * a.y + qfv[2] * a.z + qfv[3] * a.w
            + qfv[4] * bb.x + qfv[5] * bb.y + qfv[6] * bb.z + qfv[7] * bb.w
            + qfv[8] * cc.x + qfv[9] * cc.y;
    }
    rhp[j] = pack_bf16(s2[0], s2[1]);
  }
  // Q B-frag (col=q, k=dims)
  short8 qf = *reinterpret_cast<const short8*>(&Qs[qrow * 16 + hi * 8]);
  short qf2 = qf[2];
  if (hi) { qf[3] = 0; qf[4] = 0; qf[5] = 0; qf[6] = 0; qf[7] = 0; }

  float16 O;
#pragma unroll
  for (int i = 0; i < 16; ++i) O[i] = 0.f;

  const float* kg = qkv + (size_t)(b * 120 + 40 + hd * 10) * 1024;
  const float* vg = kg + 40 * 1024;

  for (int p = 0; p < 4; ++p) {
    __syncthreads();   // overlays consumed (p=0) / prev pass reads done
    for (int i = t; i < 2560; i += 256) {
      int d = i >> 8, key = i & 255;
      Ks[key * 24 + d] = f2bf(kg[d * 1024 + p * 256 + key]);
      // V column: swap bits 2<->3 of within-32 key index
      int kc = (key & 0xF3) | ((key & 4) << 1) | ((key & 8) >> 1);
      Vs[d * 264 + kc] = f2bf(vg[d * 1024 + p * 256 + key]);
    }
    Ks[t * 24 + 10] = (short)0x3F80;   // K dim10 = 1.0 (rh carrier)
#pragma unroll
    for (int d2 = 11; d2 < 16; ++d2) Ks[t * 24 + d2] = 0;  // NaN guard
    Vs[10 * 264 + t] = (short)0x3F80;  // ones-row (denominator)
    __syncthreads();

#pragma unroll
    for (int tt = 0; tt < 8; ++tt) {
      int Tl = p * 8 + tt;
      unsigned rhw = rhp[Tl >> 1];
      short rhu = (short)((Tl & 1) ? (rhw >> 16) : (rhw & 0xFFFFu));
      short8 bq = qf;
      bq[2] = hi ? rhu : qf2;
      short8 ak = *reinterpret_cast<const short8*>(&Ks[(tt * 32 + lid) * 24 + hi * 8]);
      float16 S = __builtin_amdgcn_mfma_f32_32x32x16_bf16(ak, bq, rwC, 0, 0, 0);
      // P = exp2(S); V column swap makes B-frag#1 = e[0..7], #2 = e[8..15]
      float e[16];
#pragma unroll
      for (int i = 0; i < 16; ++i) e[i] = fast_exp2(S[i]);
      uint4 b1u = make_uint4(pack_bf16(e[0], e[1]), pack_bf16(e[2], e[3]),
                             pack_bf16(e[4], e[5]), pack_bf16(e[6], e[7]));
      uint4 b2u = make_uint4(pack_bf16(e[8], e[9]), pack_bf16(e[10], e[11]),
                             pack_bf16(e[12], e[13]), pack_bf16(e[14], e[15]));
      short8 bp1 = *reinterpret_cast<short8*>(&b1u);
      short8 bp2 = *reinterpret_cast<short8*>(&b2u);
      short8 av1 = *reinterpret_cast<const short8*>(
          &Vs[(lid & 15) * 264 + tt * 32 + hi * 8]);
      short8 av2 = *reinterpret_cast<const short8*>(
          &Vs[(lid & 15) * 264 + tt * 32 + 16 + hi * 8]);
      O = __builtin_amdgcn_mfma_f32_32x32x16_bf16(av1, bp1, O, 0, 0, 0);
      O = __builtin_amdgcn_mfma_f32_32x32x16_bf16(av2, bp2, O, 0, 0, 0);
    }
  }

  // epilogue: normalize by ones-row sum (O reg 6 = row 10, hi=0 lanes), pool
  float lsum = __shfl(O[6], lid);
  float inv = 1.f / lsum;
  int nglob = qt * 128 + qrow;
  int f0 = nglob * 10;
  int c0 = f0 >> 10, c1 = (f0 + 9) >> 10;
  float s0 = 0.f, s1 = 0.f;
  if (!hi) {
#pragma unroll
    for (int r = 0; r < 4; ++r) {   // rows 0..3 = dims 0..3
      float v = O[r] * inv;
      if (((f0 + r) >> 10) == c0) s0 += v; else s1 += v;
    }
#pragma unroll
    for (int r = 4; r < 6; ++r) {   // rows 8,9 = dims 8,9
      int d = r + 4;
      float v = O[r] * inv;
      if (((f0 + d) >> 10) == c0) s0 += v; else s1 += v;
    }
  } else {
#pragma unroll
    for (int r = 0; r < 4; ++r) {   // rows 4..7 = dims 4..7
      int d = r + 4;
      float v = O[r] * inv;
      if (((f0 + d) >> 10) == c0) s0 += v; else s1 += v;
    }
  }
  atomicAdd(&poolL[c0], s0);        // LDS atomics only
  if (c1 != c0) atomicAdd(&poolL[c1], s1);
  __syncthreads();
  if (t < 16) poolP[(size_t)bid * 16 + t] = poolL[t];   // plain store partial
}

// ---------------- final: sum partials + convo-pool matvec + attno + fc ------
__global__ __launch_bounds__(128) void final_kernel(
    const float* __restrict__ sstatP, const float* __restrict__ poolP,
    const float* __restrict__ h, const float* __restrict__ chanSP,
    const float* __restrict__ chanS2P, const float* __restrict__ bn_g,
    const float* __restrict__ bn_b,
    const float* __restrict__ convo_w, const float* __restrict__ convo_b,
    const float* __restrict__ attno_w, const float* __restrict__ attno_b,
    const float* __restrict__ fc_w, const float* __restrict__ fc_b,
    float* __restrict__ out) {
  int b = blockIdx.x;
  int t = threadIdx.x;
  __shared__ float Sl[576];
  __shared__ float pooled[128];
  __shared__ float pa[40];
  if (t < 64) {
    int ci = t;
    float S1 = 0.f, S2 = 0.f;
#pragma unroll
    for (int bb = 0; bb < 16; ++bb) {
      S1 += chanSP[ci * 16 + bb];
      S2 += chanS2P[ci * 16 + bb];
    }
    float mu = S1 * (1.f / 16384.f);
    float var = S2 * (1.f / 16384.f) - mu * mu;
    float sc = bn_g[ci] * rsqrtf(var + 1e-5f);
    float sh = bn_b[ci] - mu * sc;
    const float* hp = h + (size_t)(b * 64 + ci) * 1024;
    float h00 = fmaxf(0.f, hp[0] * sc + sh);
    float h0c = fmaxf(0.f, hp[31] * sc + sh);
    float hr0 = fmaxf(0.f, hp[992] * sc + sh);
    float hrc = fmaxf(0.f, hp[1023] * sc + sh);
    float T = 0.f, R0 = 0.f, R31 = 0.f, C0 = 0.f, C31 = 0.f;
    const float* sp = sstatP + (size_t)(b * 64 + ci) * 80;
#pragma unroll
    for (int ckk = 0; ckk < 16; ++ckk) {
      T += sp[ckk * 5 + 0];
      R0 += sp[ckk * 5 + 1];
      R31 += sp[ckk * 5 + 2];
      C0 += sp[ckk * 5 + 3];
      C31 += sp[ckk * 5 + 4];
    }
    float xr[3] = {R31, 0.f, R0};
    float xc[3] = {C31, 0.f, C0};
    float corner[3][3] = {{hrc, 0.f, hr0}, {0.f, 0.f, 0.f}, {h0c, 0.f, h00}};
#pragma unroll
    for (int dy = 0; dy < 3; ++dy)
#pragma unroll
      for (int dx = 0; dx < 3; ++dx)
        Sl[ci * 9 + dy * 3 + dx] = T - xr[dy] - xc[dx] + corner[dy][dx];
  }
  if (t < 40) {
    int hd = t / 10, j = t - hd * 10;
    const float* pp = poolP + (size_t)((b * 4 + hd) * 8) * 16 + j;
    float s = 0.f;
#pragma unroll
    for (int q = 0; q < 8; ++q) s += pp[q * 16];
    pa[t] = s * (1.f / 1024.f);
  }
  __syncthreads();
  if (t < 88) {
    const float4* wr = reinterpret_cast<const float4*>(convo_w + t * 576);
    float acc = 0.f;
    for (int j = 0; j < 144; ++j) {
      float4 v = wr[j];
      acc += v.x * Sl[j * 4] + v.y * Sl[j * 4 + 1] + v.z * Sl[j * 4 + 2] + v.w * Sl[j * 4 + 3];
    }
    pooled[t] = convo_b[t] + acc * (1.f / 1024.f);
  } else if (t < 128) {
    int co = t - 88;
    const float4* wr = reinterpret_cast<const float4*>(attno_w + co * 40);
    float acc = attno_b[co];
    for (int j = 0; j < 10; ++j) {
      float4 v = wr[j];
      acc += v.x * pa[j * 4] + v.y * pa[j * 4 + 1] + v.z * pa[j * 4 + 2] + v.w * pa[j * 4 + 3];
    }
    pooled[88 + co] = acc;
  }
  __syncthreads();
  if (t < 100) {
    const float4* fr = reinterpret_cast<const float4*>(fc_w + t * 128);
    float acc = fc_b[t];
    for (int j = 0; j < 32; ++j) {
      float4 v = fr[j];
      acc += v.x * pooled[j * 4] + v.y * pooled[j * 4 + 1] + v.z * pooled[j * 4 + 2] + v.w * pooled[j * 4 + 3];
    }
    out[b * 100 + t] = acc;
  }
}

extern "C" void kernel_launch(void* const* d_in, const int* in_sizes, int n_in,
                              void* d_out, int out_size, void* d_ws, size_t ws_size,
                              hipStream_t stream) {
  const float* x         = (const float*)d_in[0];
  const float* conv1_w   = (const float*)d_in[1];
  const float* conv1_b   = (const float*)d_in[2];
  const float* bn1_g     = (const float*)d_in[3];
  const float* bn1_b     = (const float*)d_in[4];
  const float* convo_w   = (const float*)d_in[5];
  const float* convo_b   = (const float*)d_in[6];
  const float* qkv_w     = (const float*)d_in[7];
  const float* qkv_b     = (const float*)d_in[8];
  const float* attno_w   = (const float*)d_in[9];
  const float* attno_b   = (const float*)d_in[10];
  const float* key_rel_h = (const float*)d_in[11];
  const float* key_rel_w = (const float*)d_in[12];
  const float* fc_w      = (const float*)d_in[13];
  const float* fc_b      = (const float*)d_in[14];

  float* ws       = (float*)d_ws;
  float* h        = ws + WS_H;
  float* qkvb     = ws + WS_QKV;
  float* chanSP   = ws + WS_CHANS;
  float* chanS2P  = ws + WS_CHANS2;
  float* sstatP   = ws + WS_SSTATP;
  float* poolP    = ws + WS_POOLP;

  conv1_kernel<<<512, 256, 0, stream>>>(x, conv1_w, conv1_b, h, chanSP, chanS2P);
  qkv_kernel3<<<512, 256, 0, stream>>>(h, chanSP, chanS2P, bn1_g, bn1_b,
                                       qkv_w, qkv_b, qkvb, sstatP);
  attn_mfma_kernel<<<512, 256, 0, stream>>>(qkvb, key_rel_w, key_rel_h, poolP);
  final_kernel<<<16, 128, 0, stream>>>(sstatP, poolP, h, chanSP, chanS2P,
                                       bn1_g, bn1_b, convo_w, convo_b,
                                       attno_w, attno_b, fc_w, fc_b, (float*)d_out);
}